// Round 1
// baseline (288.875 us; speedup 1.0000x reference)
//
#include <hip/hip_runtime.h>
#include <hip/hip_bf16.h>

#define NROWS 8192
#define DDIM  256
#define INV_TEMP 20.0f   // 1/0.05

typedef __attribute__((ext_vector_type(8))) short bf16x8;
typedef __attribute__((ext_vector_type(4))) float f32x4;

// ---------------------------------------------------------------------------
// Kernel 1: per-row L2-normalize q and p (fp32), emit bf16 copies, fp32 diag
// dot, and zero the lse accumulator. One wave (64 threads) per row.
// ---------------------------------------------------------------------------
__global__ __launch_bounds__(64) void norm_diag_kernel(
    const float* __restrict__ q, const float* __restrict__ p,
    unsigned short* __restrict__ qn, unsigned short* __restrict__ pn,
    float* __restrict__ diag, float* __restrict__ lse)
{
    const int row  = blockIdx.x;
    const int lane = threadIdx.x;          // 0..63, 4 floats each = 256

    const float4 qv = ((const float4*)(q + (size_t)row * DDIM))[lane];
    const float4 pv = ((const float4*)(p + (size_t)row * DDIM))[lane];

    float sq = qv.x*qv.x + qv.y*qv.y + qv.z*qv.z + qv.w*qv.w;
    float sp = pv.x*pv.x + pv.y*pv.y + pv.z*pv.z + pv.w*pv.w;
    #pragma unroll
    for (int m = 1; m < 64; m <<= 1) {
        sq += __shfl_xor(sq, m);
        sp += __shfl_xor(sp, m);
    }
    const float qs = 1.0f / fmaxf(sqrtf(sq), 1e-8f);
    const float ps = 1.0f / fmaxf(sqrtf(sp), 1e-8f);

    const float qx = qv.x*qs, qy = qv.y*qs, qz = qv.z*qs, qw = qv.w*qs;
    const float px = pv.x*ps, py = pv.y*ps, pz = pv.z*ps, pw = pv.w*ps;

    // fp32 diagonal similarity (scaled by 1/T)
    float d = qx*px + qy*py + qz*pz + qw*pw;
    #pragma unroll
    for (int m = 1; m < 64; m <<= 1) d += __shfl_xor(d, m);
    if (lane == 0) {
        diag[row] = d * INV_TEMP;
        lse[row]  = 0.0f;   // zero accumulator for kernel 2 (ws is poisoned)
    }

    // pack 4 bf16 (RNE) -> 8 bytes, coalesced store
    union { unsigned short u16[4]; uint2 v; } uq, up;
    {
        __hip_bfloat16 b;
        b = __float2bfloat16(qx); uq.u16[0] = *(unsigned short*)&b;
        b = __float2bfloat16(qy); uq.u16[1] = *(unsigned short*)&b;
        b = __float2bfloat16(qz); uq.u16[2] = *(unsigned short*)&b;
        b = __float2bfloat16(qw); uq.u16[3] = *(unsigned short*)&b;
        b = __float2bfloat16(px); up.u16[0] = *(unsigned short*)&b;
        b = __float2bfloat16(py); up.u16[1] = *(unsigned short*)&b;
        b = __float2bfloat16(pz); up.u16[2] = *(unsigned short*)&b;
        b = __float2bfloat16(pw); up.u16[3] = *(unsigned short*)&b;
    }
    *(uint2*)(qn + (size_t)row * DDIM + lane * 4) = uq.v;
    *(uint2*)(pn + (size_t)row * DDIM + lane * 4) = up.v;
}

// ---------------------------------------------------------------------------
// Kernel 2: fused sim-GEMM + sum-exp. One wave per block.
// Wave owns 64 Q-rows (entire 64x256 A-tile in 128 VGPRs, loaded once) and a
// 256-column chunk of P streamed as B-fragments straight from L2.
// MFMA 16x16x32 bf16:
//   A frag: lane holds A[m = lane&15][k = (lane>>4)*8 + j]   (contig 8 bf16)
//   B frag: lane holds B[k = (lane>>4)*8 + j][n = lane&15] = P[n][k] (contig)
//   C/D:    col = lane&15, row = (lane>>4)*4 + reg            (m89-verified)
// No max subtraction: |sim| <= 20 so exp() cannot overflow fp32.
// ---------------------------------------------------------------------------
__global__ __launch_bounds__(64, 2) void simexp_kernel(
    const unsigned short* __restrict__ qn,
    const unsigned short* __restrict__ pn,
    float* __restrict__ lse)
{
    const int lane = threadIdx.x;
    const int quad = lane >> 4;
    const int l16  = lane & 15;
    const int row_base = blockIdx.y * 64;     // 128 row-blocks
    const int col_base = blockIdx.x * 256;    // 32 col-chunks

    // Load full A tile: 4 row-tiles x 8 k-steps = 128 VGPRs
    bf16x8 a[4][8];
    #pragma unroll
    for (int rt = 0; rt < 4; ++rt)
        #pragma unroll
        for (int ks = 0; ks < 8; ++ks)
            a[rt][ks] = *(const bf16x8*)(qn +
                (size_t)(row_base + rt * 16 + l16) * DDIM + ks * 32 + quad * 8);

    float lsum[4][4];
    #pragma unroll
    for (int rt = 0; rt < 4; ++rt)
        #pragma unroll
        for (int r = 0; r < 4; ++r) lsum[rt][r] = 0.0f;

    for (int ci = 0; ci < 8; ++ci) {          // 8 x 32 columns = 256
        const int col0 = col_base + ci * 32;

        f32x4 acc[4][2];
        #pragma unroll
        for (int rt = 0; rt < 4; ++rt) {
            acc[rt][0] = (f32x4)0.0f;
            acc[rt][1] = (f32x4)0.0f;
        }

        #pragma unroll
        for (int ks = 0; ks < 8; ++ks) {
            const bf16x8 b0 = *(const bf16x8*)(pn +
                (size_t)(col0 + l16) * DDIM + ks * 32 + quad * 8);
            const bf16x8 b1 = *(const bf16x8*)(pn +
                (size_t)(col0 + 16 + l16) * DDIM + ks * 32 + quad * 8);
            #pragma unroll
            for (int rt = 0; rt < 4; ++rt) {
                acc[rt][0] = __builtin_amdgcn_mfma_f32_16x16x32_bf16(
                    a[rt][ks], b0, acc[rt][0], 0, 0, 0);
                acc[rt][1] = __builtin_amdgcn_mfma_f32_16x16x32_bf16(
                    a[rt][ks], b1, acc[rt][1], 0, 0, 0);
            }
        }

        // epilogue: sum exp(sim) per (row held by this lane)
        #pragma unroll
        for (int rt = 0; rt < 4; ++rt)
            #pragma unroll
            for (int r = 0; r < 4; ++r)
                lsum[rt][r] += __expf(acc[rt][0][r] * INV_TEMP)
                             + __expf(acc[rt][1][r] * INV_TEMP);
    }

    // reduce across the 16 lanes of each quad (same row, different cols)
    #pragma unroll
    for (int rt = 0; rt < 4; ++rt)
        #pragma unroll
        for (int r = 0; r < 4; ++r) {
            float v = lsum[rt][r];
            v += __shfl_xor(v, 1);
            v += __shfl_xor(v, 2);
            v += __shfl_xor(v, 4);
            v += __shfl_xor(v, 8);
            if (l16 == 0)
                atomicAdd(&lse[row_base + rt * 16 + quad * 4 + r], v);
        }
}

// ---------------------------------------------------------------------------
// Kernel 3: loss = mean(log(lse) - diag). Single block.
// ---------------------------------------------------------------------------
__global__ __launch_bounds__(256) void finalize_kernel(
    const float* __restrict__ lse, const float* __restrict__ diag,
    float* __restrict__ out)
{
    float s = 0.0f;
    for (int i = threadIdx.x; i < NROWS; i += 256)
        s += logf(lse[i]) - diag[i];
    #pragma unroll
    for (int m = 1; m < 64; m <<= 1) s += __shfl_xor(s, m);

    __shared__ float wsum[4];
    if ((threadIdx.x & 63) == 0) wsum[threadIdx.x >> 6] = s;
    __syncthreads();
    if (threadIdx.x == 0)
        out[0] = (wsum[0] + wsum[1] + wsum[2] + wsum[3]) * (1.0f / NROWS);
}

// ---------------------------------------------------------------------------
extern "C" void kernel_launch(void* const* d_in, const int* in_sizes, int n_in,
                              void* d_out, int out_size, void* d_ws, size_t ws_size,
                              hipStream_t stream)
{
    const float* q = (const float*)d_in[0];
    const float* p = (const float*)d_in[1];

    char* ws = (char*)d_ws;
    unsigned short* qn = (unsigned short*)ws;                        // 4 MB
    unsigned short* pn = (unsigned short*)(ws + (size_t)NROWS*DDIM*2); // 4 MB
    float* diag = (float*)(ws + 2 * (size_t)NROWS * DDIM * 2);       // 32 KB
    float* lse  = diag + NROWS;                                      // 32 KB

    norm_diag_kernel<<<NROWS, 64, 0, stream>>>(q, p, qn, pn, diag, lse);

    dim3 grid(32, 128);   // col-chunks x row-blocks = 1024 one-wave blocks
    simexp_kernel<<<grid, 64, 0, stream>>>(qn, pn, lse);

    finalize_kernel<<<1, 256, 0, stream>>>(lse, diag, (float*)d_out);
}

// Round 2
// 147.151 us; speedup vs baseline: 1.9631x; 1.9631x over previous
//
#include <hip/hip_runtime.h>
#include <hip/hip_bf16.h>

#define NROWS 8192
#define DDIM  256
#define INV_TEMP 20.0f   // 1/0.05

typedef __attribute__((ext_vector_type(8))) short bf16x8;
typedef __attribute__((ext_vector_type(4))) float f32x4;

// async global->LDS, 16B per lane. LDS dest = uniform base + lane*16.
__device__ static inline void async16(const void* g, void* l) {
    __builtin_amdgcn_global_load_lds(
        (const __attribute__((address_space(1))) void*)g,
        (__attribute__((address_space(3))) void*)l, 16, 0, 0);
}

// ---------------------------------------------------------------------------
// Kernel 1: per-row L2-normalize q and p (fp32), emit bf16 copies, fp32 diag.
// One wave per row.
// ---------------------------------------------------------------------------
__global__ __launch_bounds__(64) void norm_diag_kernel(
    const float* __restrict__ q, const float* __restrict__ p,
    unsigned short* __restrict__ qn, unsigned short* __restrict__ pn,
    float* __restrict__ diag)
{
    const int row  = blockIdx.x;
    const int lane = threadIdx.x;

    const float4 qv = ((const float4*)(q + (size_t)row * DDIM))[lane];
    const float4 pv = ((const float4*)(p + (size_t)row * DDIM))[lane];

    float sq = qv.x*qv.x + qv.y*qv.y + qv.z*qv.z + qv.w*qv.w;
    float sp = pv.x*pv.x + pv.y*pv.y + pv.z*pv.z + pv.w*pv.w;
    #pragma unroll
    for (int m = 1; m < 64; m <<= 1) {
        sq += __shfl_xor(sq, m);
        sp += __shfl_xor(sp, m);
    }
    const float qs = 1.0f / fmaxf(sqrtf(sq), 1e-8f);
    const float ps = 1.0f / fmaxf(sqrtf(sp), 1e-8f);

    const float qx = qv.x*qs, qy = qv.y*qs, qz = qv.z*qs, qw = qv.w*qs;
    const float px = pv.x*ps, py = pv.y*ps, pz = pv.z*ps, pw = pv.w*ps;

    float d = qx*px + qy*py + qz*pz + qw*pw;
    #pragma unroll
    for (int m = 1; m < 64; m <<= 1) d += __shfl_xor(d, m);
    if (lane == 0) diag[row] = d * INV_TEMP;

    union { unsigned short u16[4]; uint2 v; } uq, up;
    {
        __hip_bfloat16 b;
        b = __float2bfloat16(qx); uq.u16[0] = *(unsigned short*)&b;
        b = __float2bfloat16(qy); uq.u16[1] = *(unsigned short*)&b;
        b = __float2bfloat16(qz); uq.u16[2] = *(unsigned short*)&b;
        b = __float2bfloat16(qw); uq.u16[3] = *(unsigned short*)&b;
        b = __float2bfloat16(px); up.u16[0] = *(unsigned short*)&b;
        b = __float2bfloat16(py); up.u16[1] = *(unsigned short*)&b;
        b = __float2bfloat16(pz); up.u16[2] = *(unsigned short*)&b;
        b = __float2bfloat16(pw); up.u16[3] = *(unsigned short*)&b;
    }
    *(uint2*)(qn + (size_t)row * DDIM + lane * 4) = uq.v;
    *(uint2*)(pn + (size_t)row * DDIM + lane * 4) = up.v;
}

// ---------------------------------------------------------------------------
// Kernel 2: m97-style fused GEMM + sum-exp.
// Block = 256 threads (4 waves, 2x2 wave grid), tile = 128 rows x 128 cols,
// K-loop: 8 steps of BK=32 (64 B/row), A/B staged to LDS via global_load_lds.
// LDS chunk layout per 16-row tile: [quad][l16] x 16B -> fragment ds_read_b128
// is linear (bank stride 4 -> 2-way aliasing = free).
// Each wave: 4x4 acc tiles (64 VGPRs), 16 MFMAs/K-step.
// Epilogue: exp (no max needed, |sim|<=20), quad-shuffle row sums, LDS combine
// across the two col-waves, write per-colblock partial rowsums (no atomics).
// ---------------------------------------------------------------------------
__global__ __launch_bounds__(256, 2) void simexp_kernel(
    const unsigned short* __restrict__ qn,
    const unsigned short* __restrict__ pn,
    float* __restrict__ part)       // [64 colblocks][8192 rows]
{
    __shared__ unsigned char lds[16384];   // As: 8 KB | Bs: 8 KB

    const int tid  = threadIdx.x;
    const int lane = tid & 63;
    const int w    = tid >> 6;        // wave 0..3
    const int wr   = w >> 1;          // wave row (0..1)
    const int wc   = w & 1;           // wave col (0..1)
    const int quad = lane >> 4;
    const int l16  = lane & 15;
    const int rowbase = blockIdx.y * 128;
    const int colbase = blockIdx.x * 128;

    // staging source addresses: wave w stages A row-tiles {2w, 2w+1} and
    // B col-tiles {2w, 2w+1}. lane l -> row (l&15), 16B chunk (l>>4).
    const unsigned short* gA0 = qn + (size_t)(rowbase + (2*w  )*16 + l16) * DDIM + quad * 8;
    const unsigned short* gA1 = qn + (size_t)(rowbase + (2*w+1)*16 + l16) * DDIM + quad * 8;
    const unsigned short* gB0 = pn + (size_t)(colbase + (2*w  )*16 + l16) * DDIM + quad * 8;
    const unsigned short* gB1 = pn + (size_t)(colbase + (2*w+1)*16 + l16) * DDIM + quad * 8;

    unsigned char* ldsA = lds;
    unsigned char* ldsB = lds + 8192;

    f32x4 acc[4][4];
    #pragma unroll
    for (int i = 0; i < 4; ++i)
        #pragma unroll
        for (int j = 0; j < 4; ++j) acc[i][j] = (f32x4)0.0f;

    for (int ks = 0; ks < 8; ++ks) {
        __syncthreads();               // prev step's ds_reads done
        async16(gA0 + ks * 32, ldsA + (2*w    ) * 1024);
        async16(gA1 + ks * 32, ldsA + (2*w + 1) * 1024);
        async16(gB0 + ks * 32, ldsB + (2*w    ) * 1024);
        async16(gB1 + ks * 32, ldsB + (2*w + 1) * 1024);
        __syncthreads();               // staging complete (vmcnt drained)

        bf16x8 af[4], bf[4];
        #pragma unroll
        for (int i = 0; i < 4; ++i)
            af[i] = *(const bf16x8*)(ldsA + (wr*4 + i) * 1024 + quad * 256 + l16 * 16);
        #pragma unroll
        for (int j = 0; j < 4; ++j)
            bf[j] = *(const bf16x8*)(ldsB + (wc*4 + j) * 1024 + quad * 256 + l16 * 16);

        #pragma unroll
        for (int i = 0; i < 4; ++i)
            #pragma unroll
            for (int j = 0; j < 4; ++j)
                acc[i][j] = __builtin_amdgcn_mfma_f32_16x16x32_bf16(
                    af[i], bf[j], acc[i][j], 0, 0, 0);
    }

    // epilogue ------------------------------------------------------------
    __syncthreads();                   // done with staged tiles; reuse LDS
    float* red = (float*)lds;          // 256 floats: [wc][128 rows]

    #pragma unroll
    for (int i = 0; i < 4; ++i)
        #pragma unroll
        for (int r = 0; r < 4; ++r) {
            float s = __expf(acc[i][0][r] * INV_TEMP)
                    + __expf(acc[i][1][r] * INV_TEMP)
                    + __expf(acc[i][2][r] * INV_TEMP)
                    + __expf(acc[i][3][r] * INV_TEMP);
            s += __shfl_xor(s, 1);
            s += __shfl_xor(s, 2);
            s += __shfl_xor(s, 4);
            s += __shfl_xor(s, 8);
            if (l16 == 0)
                red[wc * 128 + wr * 64 + i * 16 + quad * 4 + r] = s;
        }
    __syncthreads();

    if (tid < 128)
        part[(size_t)blockIdx.x * NROWS + rowbase + tid] = red[tid] + red[128 + tid];
}

// ---------------------------------------------------------------------------
// Kernel 3: per-row total + log - diag, block-partial loss sums.
// 64 blocks x 128 threads; block b owns rows [b*128, b*128+128).
// ---------------------------------------------------------------------------
__global__ __launch_bounds__(128) void rowsum_kernel(
    const float* __restrict__ part, const float* __restrict__ diag,
    float* __restrict__ loss_part)
{
    const int row = blockIdx.x * 128 + threadIdx.x;
    float s = 0.0f;
    #pragma unroll 4
    for (int cb = 0; cb < 64; ++cb)
        s += part[(size_t)cb * NROWS + row];     // coalesced across threads
    float v = logf(s) - diag[row];

    #pragma unroll
    for (int m = 1; m < 64; m <<= 1) v += __shfl_xor(v, m);
    __shared__ float wsum[2];
    if ((threadIdx.x & 63) == 0) wsum[threadIdx.x >> 6] = v;
    __syncthreads();
    if (threadIdx.x == 0) loss_part[blockIdx.x] = wsum[0] + wsum[1];
}

// ---------------------------------------------------------------------------
// Kernel 4: final mean over 64 block partials. One wave.
// ---------------------------------------------------------------------------
__global__ __launch_bounds__(64) void final_kernel(
    const float* __restrict__ loss_part, float* __restrict__ out)
{
    float v = loss_part[threadIdx.x];
    #pragma unroll
    for (int m = 1; m < 64; m <<= 1) v += __shfl_xor(v, m);
    if (threadIdx.x == 0) out[0] = v * (1.0f / NROWS);
}

// ---------------------------------------------------------------------------
extern "C" void kernel_launch(void* const* d_in, const int* in_sizes, int n_in,
                              void* d_out, int out_size, void* d_ws, size_t ws_size,
                              hipStream_t stream)
{
    const float* q = (const float*)d_in[0];
    const float* p = (const float*)d_in[1];

    char* ws = (char*)d_ws;
    unsigned short* qn   = (unsigned short*)ws;                          // 4 MB
    unsigned short* pn   = (unsigned short*)(ws + (size_t)NROWS*DDIM*2); // 4 MB
    float* part      = (float*)(ws + 2*(size_t)NROWS*DDIM*2);            // 2 MB
    float* diag      = part + 64 * (size_t)NROWS;                        // 32 KB
    float* loss_part = diag + NROWS;                                     // 256 B

    norm_diag_kernel<<<NROWS, 64, 0, stream>>>(q, p, qn, pn, diag);

    dim3 grid(64, 64);   // colblocks x rowblocks
    simexp_kernel<<<grid, 256, 0, stream>>>(qn, pn, part);

    rowsum_kernel<<<64, 128, 0, stream>>>(part, diag, loss_part);
    final_kernel<<<1, 64, 0, stream>>>(loss_part, (float*)d_out);
}